// Round 16
// baseline (213.274 us; speedup 1.0000x reference)
//
#include <hip/hip_runtime.h>
#include <math.h>

constexpr int Lq = 8, Cq = 16, Hq = 240, Wq = 480, MIDq = 8, SEM = 4;
constexpr int HWq = Hq * Wq;
constexpr int TW = 120, TR = 4, SR = 6, SW = 128;   // tile: 4 out rows x 120 px; stage 6 rows x 128 (padded)

__device__ __forceinline__ float sigmoidf_(float v) { return 1.0f / (1.0f + expf(-v)); }

// conv1: x (L,16,H,W) -> silu -> f1 (L,8,H,W), 3x3 SAME zero-pad.
// R16: two-phase. Phase 1 stages the 6x16x122 input tile into LDS with a
// copy-shaped loop (unit-stride coalesced, unroll 8 -> 8 loads in flight per
// wave). Phase 2 does all FMAs from LDS (no global latency on critical path).
// FMA chains ordered identically to R5 -> bit-identical output.
__global__ __launch_bounds__(256, 2) void k_conv1(const float* __restrict__ x,
                        const float* __restrict__ w1,
                        const float* __restrict__ b1, float* __restrict__ f1) {
    __shared__ float sm[Cq][SR][SW];
    int b = blockIdx.x;
    int l = b & 7;                    // frame -> XCD pinned
    int rest = b >> 3;                // 0..239
    int strip = rest >> 2;            // 0..59
    int tilex = rest & 3;             // 0..3
    int y0 = strip * TR;
    int gx0 = tilex * TW - 1;
    int t = threadIdx.x;
    const float* xb = x + (size_t)l * Cq * HWq;

    constexpr int NS = Cq * SR * SW;  // 12288 = 48*256 exact
#pragma unroll 8
    for (int it = 0; it < NS / 256; it++) {
        int s = it * 256 + t;
        int ic = s / (SR * SW);
        int rem = s - ic * (SR * SW);
        int xr = rem / SW;
        int j = rem - xr * SW;
        int gy = y0 - 1 + xr;
        int gx = gx0 + j;
        float v = 0.f;
        if (gy >= 0 && gy < Hq && gx >= 0 && gx < Wq)
            v = xb[(size_t)ic * HWq + gy * Wq + gx];
        sm[ic][xr][j] = v;
    }
    __syncthreads();
    if (t >= 2 * TW) return;
    int sub = t / TW;                 // 0: out rows 0-1, 1: out rows 2-3
    int px = t - sub * TW;

    float acc[2][MIDq];
#pragma unroll
    for (int oo = 0; oo < 2; oo++)
#pragma unroll
        for (int m = 0; m < MIDq; m++) acc[oo][m] = b1[m];

#pragma unroll 1
    for (int ic = 0; ic < Cq; ic++) {
        float in4[4][3];
#pragma unroll
        for (int i = 0; i < 4; i++) {
            in4[i][0] = sm[ic][sub * 2 + i][px];
            in4[i][1] = sm[ic][sub * 2 + i][px + 1];
            in4[i][2] = sm[ic][sub * 2 + i][px + 2];
        }
#pragma unroll
        for (int oo = 0; oo < 2; oo++) {
#pragma unroll
            for (int kr = 0; kr < 3; kr++) {
#pragma unroll
                for (int m = 0; m < MIDq; m++) {
                    const float* wp = w1 + ((size_t)m * Cq + ic) * 9 + kr * 3;
                    acc[oo][m] = fmaf(wp[0], in4[oo + kr][0],
                                 fmaf(wp[1], in4[oo + kr][1],
                                 fmaf(wp[2], in4[oo + kr][2], acc[oo][m])));
                }
            }
        }
    }
    size_t base_out = (size_t)(y0 + sub * 2) * Wq + tilex * TW + px;
#pragma unroll
    for (int oo = 0; oo < 2; oo++)
#pragma unroll
        for (int m = 0; m < MIDq; m++) {
            float a = acc[oo][m];
            f1[(size_t)(l * MIDq + m) * HWq + base_out + (size_t)oo * Wq] = a * sigmoidf_(a);
        }
}

// conv2: f1 (L,8,H,W) -> f (L,2,H,W). Same two-phase structure.
__global__ __launch_bounds__(256, 2) void k_conv2(const float* __restrict__ f1,
                        const float* __restrict__ w2,
                        const float* __restrict__ b2, float* __restrict__ f) {
    __shared__ float sm[MIDq][SR][SW];
    int b = blockIdx.x;
    int l = b & 7;
    int rest = b >> 3;
    int strip = rest >> 2;
    int tilex = rest & 3;
    int y0 = strip * TR;
    int gx0 = tilex * TW - 1;
    int t = threadIdx.x;
    const float* fb = f1 + (size_t)l * MIDq * HWq;

    constexpr int NS = MIDq * SR * SW;   // 6144 = 24*256 exact
#pragma unroll 8
    for (int it = 0; it < NS / 256; it++) {
        int s = it * 256 + t;
        int ic = s / (SR * SW);
        int rem = s - ic * (SR * SW);
        int xr = rem / SW;
        int j = rem - xr * SW;
        int gy = y0 - 1 + xr;
        int gx = gx0 + j;
        float v = 0.f;
        if (gy >= 0 && gy < Hq && gx >= 0 && gx < Wq)
            v = fb[(size_t)ic * HWq + gy * Wq + gx];
        sm[ic][xr][j] = v;
    }
    __syncthreads();
    if (t >= 2 * TW) return;
    int sub = t / TW;
    int px = t - sub * TW;

    float acc[2][2];
#pragma unroll
    for (int oo = 0; oo < 2; oo++)
#pragma unroll
        for (int m = 0; m < 2; m++) acc[oo][m] = b2[m];

#pragma unroll 1
    for (int ic = 0; ic < MIDq; ic++) {
        float in4[4][3];
#pragma unroll
        for (int i = 0; i < 4; i++) {
            in4[i][0] = sm[ic][sub * 2 + i][px];
            in4[i][1] = sm[ic][sub * 2 + i][px + 1];
            in4[i][2] = sm[ic][sub * 2 + i][px + 2];
        }
#pragma unroll
        for (int oo = 0; oo < 2; oo++) {
#pragma unroll
            for (int kr = 0; kr < 3; kr++) {
#pragma unroll
                for (int m = 0; m < 2; m++) {
                    const float* wp = w2 + ((size_t)m * MIDq + ic) * 9 + kr * 3;
                    acc[oo][m] = fmaf(wp[0], in4[oo + kr][0],
                                 fmaf(wp[1], in4[oo + kr][1],
                                 fmaf(wp[2], in4[oo + kr][2], acc[oo][m])));
                }
            }
        }
    }
    size_t base_out = (size_t)(y0 + sub * 2) * Wq + tilex * TW + px;
#pragma unroll
    for (int oo = 0; oo < 2; oo++)
#pragma unroll
        for (int m = 0; m < 2; m++)
            f[(size_t)(l * 2 + m) * HWq + base_out + (size_t)oo * Wq] = acc[oo][m];
}

// sobel (wrap-x, edge-y) + metric + tanh -> flow (L,2,H,W) (R5 exact)
__global__ void k_flow(const float* __restrict__ f, float* __restrict__ flow) {
    int idx = blockIdx.x * blockDim.x + threadIdx.x;
    if (idx >= Lq * HWq) return;
    int l = idx / HWq, rem = idx % HWq, y = rem / Wq, x = rem % Wq;
    const float* phi = f + (size_t)(l * 2 + 0) * HWq;
    const float* psi = f + (size_t)(l * 2 + 1) * HWq;
    float ph[3][3], ps[3][3];
#pragma unroll
    for (int i = 0; i < 3; i++) {
        int yy = y + i - 1;
        yy = yy < 0 ? 0 : (yy >= Hq ? Hq - 1 : yy);
#pragma unroll
        for (int j = 0; j < 3; j++) {
            int xx = x + j - 1;
            xx = (xx + Wq) % Wq;
            ph[i][j] = phi[yy * Wq + xx];
            ps[i][j] = psi[yy * Wq + xx];
        }
    }
    float gxp = (ph[0][2] - ph[0][0]) + 2.f * (ph[1][2] - ph[1][0]) + (ph[2][2] - ph[2][0]);
    float gyp = (ph[2][0] + 2.f * ph[2][1] + ph[2][2]) - (ph[0][0] + 2.f * ph[0][1] + ph[0][2]);
    float gxs = (ps[0][2] - ps[0][0]) + 2.f * (ps[1][2] - ps[1][0]) + (ps[2][2] - ps[2][0]);
    float gys = (ps[2][0] + 2.f * ps[2][1] + ps[2][2]) - (ps[0][0] + 2.f * ps[0][1] + ps[0][2]);
    float latf = (float)(-M_PI * 0.5 + (double)y * (M_PI / (double)(Hq - 1)));
    float metric = (float)(1.0 / (cos((double)latf) + 1e-6));
    float u = gxp * metric - gys;
    float v = gyp + gxs * metric;
    flow[(size_t)(l * 2 + 0) * HWq + rem] = tanhf(u);
    flow[(size_t)(l * 2 + 1) * HWq + rem] = tanhf(v);
}

// one-time: m0[px][c] = mean_r h0[c][px][r]   (h0: (C,H,W,R) fp32, R=8)
__global__ void k_m0(const float* __restrict__ h0, float* __restrict__ m0) {
    int px = blockIdx.x * 256 + threadIdx.x;
    const float4* h4 = (const float4*)h0;
    float4* mp = (float4*)(m0 + (size_t)px * Cq);
#pragma unroll
    for (int cq = 0; cq < 4; cq++) {
        float vals[4];
#pragma unroll
        for (int cc = 0; cc < 4; cc++) {
            int c = cq * 4 + cc;
            float4 a = h4[(size_t)(c * HWq + px) * 2];
            float4 b = h4[(size_t)(c * HWq + px) * 2 + 1];
            vals[cc] = (a.x + a.y + a.z + a.w + b.x + b.y + b.z + b.w) * 0.125f;
        }
        float4 o = {vals[0], vals[1], vals[2], vals[3]};
        mp[cq] = o;
    }
}

// Fused scan step (R11 form: 2 barriers, SE recomputed in registers).
__global__ __launch_bounds__(1024) void k_step(const float* __restrict__ min_,
                       float* __restrict__ mout, const float* __restrict__ flow_l,
                       const float* __restrict__ xl, const float* __restrict__ listT,
                       int l,
                       const float* __restrict__ sw1, const float* __restrict__ sb1,
                       const float* __restrict__ sw2, const float* __restrict__ sb2,
                       float* __restrict__ out_l) {
    constexpr int STR = 17;                     // LDS row stride (coprime 32)
    __shared__ float sm[Wq * STR];
    __shared__ float csum[Cq];

    int y = blockIdx.x;
    int t = threadIdx.x;
    int wave = t >> 6, lane = t & 63;
    bool act = t < 2 * Wq;
    int px = act ? (t >> 1) : (Wq - 1);
    int half = t & 1;
    int c0 = half * 8;

    float dt = listT[l];
    float mn[8];
    {
        float u = flow_l[y * Wq + px];
        float v = flow_l[HWq + y * Wq + px];
        float gx = (px * (2.0f / (Wq - 1)) - 1.0f) - u * dt;
        float gy = (y * (2.0f / (Hq - 1)) - 1.0f) - v * dt;
        float xp = fminf(fmaxf((gx + 1.0f) * (Wq * 0.5f) - 0.5f, 0.0f), (float)(Wq - 1));
        float yp = fminf(fmaxf((gy + 1.0f) * (Hq * 0.5f) - 0.5f, 0.0f), (float)(Hq - 1));
        float x0f = floorf(xp), y0f = floorf(yp);
        float wx = xp - x0f, wy = yp - y0f;
        int x0 = (int)x0f, y0 = (int)y0f;
        int x1 = min(x0 + 1, Wq - 1), y1 = min(y0 + 1, Hq - 1);
        const float4* m4 = (const float4*)min_;
        size_t b00 = (size_t)(y0 * Wq + x0) * 4 + (half * 2);
        size_t b01 = (size_t)(y0 * Wq + x1) * 4 + (half * 2);
        size_t b10 = (size_t)(y1 * Wq + x0) * 4 + (half * 2);
        size_t b11 = (size_t)(y1 * Wq + x1) * 4 + (half * 2);
        float4 A0 = m4[b00], A1 = m4[b00 + 1];
        float4 B0 = m4[b01], B1 = m4[b01 + 1];
        float4 C0 = m4[b10], C1 = m4[b10 + 1];
        float4 D0 = m4[b11], D1 = m4[b11 + 1];
        float w00 = (1.f - wx) * (1.f - wy), w01 = wx * (1.f - wy);
        float w10 = (1.f - wx) * wy, w11 = wx * wy;
        const float* xb = xl + y * Wq + px;
        float xv[8];
#pragma unroll
        for (int j = 0; j < 8; j++) xv[j] = xb[(size_t)(c0 + j) * HWq];
        mn[0] = w00 * A0.x + w01 * B0.x + w10 * C0.x + w11 * D0.x + xv[0];
        mn[1] = w00 * A0.y + w01 * B0.y + w10 * C0.y + w11 * D0.y + xv[1];
        mn[2] = w00 * A0.z + w01 * B0.z + w10 * C0.z + w11 * D0.z + xv[2];
        mn[3] = w00 * A0.w + w01 * B0.w + w10 * C0.w + w11 * D0.w + xv[3];
        mn[4] = w00 * A1.x + w01 * B1.x + w10 * C1.x + w11 * D1.x + xv[4];
        mn[5] = w00 * A1.y + w01 * B1.y + w10 * C1.y + w11 * D1.y + xv[5];
        mn[6] = w00 * A1.z + w01 * B1.z + w10 * C1.z + w11 * D1.z + xv[6];
        mn[7] = w00 * A1.w + w01 * B1.w + w10 * C1.w + w11 * D1.w + xv[7];
    }
    if (act) {
        float4* mo = (float4*)(mout + (size_t)(y * Wq + px) * Cq + c0);
        float4 o0 = {mn[0], mn[1], mn[2], mn[3]};
        float4 o1 = {mn[4], mn[5], mn[6], mn[7]};
        mo[0] = o0;
        mo[1] = o1;
#pragma unroll
        for (int j = 0; j < 8; j++) sm[px * STR + c0 + j] = mn[j];
    }
    __syncthreads();
    {
        float s = 0.f;
#pragma unroll
        for (int k = 0; k < 8; k++) {
            int p = k * 64 + lane;
            if (p < Wq) s += sm[p * STR + wave];
        }
#pragma unroll
        for (int off = 32; off > 0; off >>= 1) s += __shfl_down(s, off, 64);
        if (lane == 0) csum[wave] = s;
    }
    __syncthreads();
    if (act) {
        float ym[Cq];
#pragma unroll
        for (int i = 0; i < Cq; i++) ym[i] = csum[i] * (1.0f / Wq);
        float z[SEM];
#pragma unroll
        for (int mm = 0; mm < SEM; mm++) {
            float a = sb1[mm];
#pragma unroll
            for (int i = 0; i < Cq; i++) a = fmaf(sw1[mm * Cq + i], ym[i], a);
            z[mm] = a * sigmoidf_(a);
        }
        float* ob = out_l + y * Wq + px;
#pragma unroll
        for (int j = 0; j < 8; j++) {
            float a = sb2[c0 + j];
#pragma unroll
            for (int mm = 0; mm < SEM; mm++) a = fmaf(sw2[(c0 + j) * SEM + mm], z[mm], a);
            ob[(size_t)(c0 + j) * HWq] = mn[j] * sigmoidf_(a);
        }
    }
}

extern "C" void kernel_launch(void* const* d_in, const int* in_sizes, int n_in,
                              void* d_out, int out_size, void* d_ws, size_t ws_size,
                              hipStream_t stream) {
    const float* x = (const float*)d_in[0];
    const float* h0 = (const float*)d_in[1];
    const float* listT = (const float*)d_in[2];
    const float* hw1 = (const float*)d_in[3];
    const float* hb1 = (const float*)d_in[4];
    const float* hw2 = (const float*)d_in[5];
    const float* hb2 = (const float*)d_in[6];
    const float* sw1 = (const float*)d_in[7];
    const float* sb1 = (const float*)d_in[8];
    const float* sw2 = (const float*)d_in[9];
    const float* sb2 = (const float*)d_in[10];
    float* out = (float*)d_out;
    char* ws = (char*)d_ws;

    size_t off = 0;
    float* flow = (float*)(ws + off); off += sizeof(float) * (size_t)Lq * 2 * HWq;
    float* f    = (float*)(ws + off); off += sizeof(float) * (size_t)Lq * 2 * HWq;
    float* f1   = (float*)(ws + off); off += sizeof(float) * (size_t)Lq * MIDq * HWq;
    float* mA   = (float*)(ws + off); off += sizeof(float) * (size_t)HWq * Cq;
    float* mB   = (float*)(ws + off); off += sizeof(float) * (size_t)HWq * Cq;

    // 8 frames x 60 strips x 4 tiles
    k_conv1<<<Lq * (Hq / TR) * 4, 256, 0, stream>>>(x, hw1, hb1, f1);
    k_conv2<<<Lq * (Hq / TR) * 4, 256, 0, stream>>>(f1, hw2, hb2, f);
    k_flow<<<(Lq * HWq + 255) / 256, 256, 0, stream>>>(f, flow);
    k_m0<<<HWq / 256, 256, 0, stream>>>(h0, mA);

    float* bufs[2] = {mA, mB};
    for (int l = 0; l < Lq; l++) {
        float* min_ = bufs[l & 1];
        float* mout = bufs[(l + 1) & 1];
        k_step<<<Hq, 1024, 0, stream>>>(min_, mout, flow + (size_t)l * 2 * HWq,
                                        x + (size_t)l * Cq * HWq, listT, l,
                                        sw1, sb1, sw2, sb2,
                                        out + (size_t)l * Cq * HWq);
    }
}

// Round 17
// 170.519 us; speedup vs baseline: 1.2507x; 1.2507x over previous
//
#include <hip/hip_runtime.h>
#include <math.h>

constexpr int Lq = 8, Cq = 16, Hq = 240, Wq = 480, MIDq = 8, SEM = 4;
constexpr int HWq = Hq * Wq;

__device__ __forceinline__ float sigmoidf_(float v) { return 1.0f / (1.0f + expf(-v)); }

// conv1: x (L,16,H,W) -> silu -> f1 (L,8,H,W), 3x3 SAME zero-pad.
// R17: R5/R10 structure EXACTLY (same loop order -> same 29MB ideal FETCH,
// same FMA chains -> bit-identical output). ONLY change: the two full-wave
// scalar edge loads (16 L1-lines each, 2/3 of all line traffic) are replaced
// by shfl of the neighbor's mid register + single-lane boundary patch loads.
__global__ void k_conv1(const float* __restrict__ x, const float* __restrict__ w1,
                        const float* __restrict__ b1, float* __restrict__ f1) {
    int b = blockIdx.x;
    int l = b & 7, y = b >> 3;
    int t = threadIdx.x;
    int lane = t & 63;
    int tc = t < 120 ? t : 119;        // dup lanes keep shfl sources defined
    int xi = tc * 4;
    float acc[MIDq][4];
#pragma unroll
    for (int m = 0; m < MIDq; m++) {
        float bv = b1[m];
#pragma unroll
        for (int o = 0; o < 4; o++) acc[m][o] = bv;
    }
#pragma unroll 1
    for (int ic = 0; ic < Cq; ic++) {
        const float* xin = x + (size_t)(l * Cq + ic) * HWq;
        const float* wrow = w1 + ic * 9;
#pragma unroll
        for (int r = 0; r < 3; r++) {
            int yy = y + r - 1;
            if (yy < 0 || yy >= Hq) continue;
            const float* rp = xin + yy * Wq;
            float4 mid = *(const float4*)(rp + xi);
            float lft = __shfl_up(mid.w, 1, 64);
            if (lane == 0) lft = (xi == 0) ? 0.f : rp[xi - 1];
            float rgt = __shfl_down(mid.x, 1, 64);
            if (lane == 63) rgt = (xi + 4 < Wq) ? rp[xi + 4] : 0.f;
            if (xi + 4 >= Wq) rgt = 0.f;
            float in6[6] = {lft, mid.x, mid.y, mid.z, mid.w, rgt};
#pragma unroll
            for (int m = 0; m < MIDq; m++) {
                const float* wp = wrow + m * (Cq * 9) + r * 3;
                float w0 = wp[0], w1v = wp[1], w2 = wp[2];
#pragma unroll
                for (int o = 0; o < 4; o++)
                    acc[m][o] = fmaf(w0, in6[o],
                                fmaf(w1v, in6[o + 1],
                                fmaf(w2, in6[o + 2], acc[m][o])));
            }
        }
    }
    if (t < 120) {
        size_t rowoff = (size_t)y * Wq + xi;
#pragma unroll
        for (int m = 0; m < MIDq; m++) {
            float4 v;
            float a0 = acc[m][0], a1 = acc[m][1], a2 = acc[m][2], a3 = acc[m][3];
            v.x = a0 * sigmoidf_(a0);
            v.y = a1 * sigmoidf_(a1);
            v.z = a2 * sigmoidf_(a2);
            v.w = a3 * sigmoidf_(a3);
            *(float4*)(f1 + (size_t)(l * MIDq + m) * HWq + rowoff) = v;
        }
    }
}

// conv2: f1 (L,8,H,W) -> f (L,2,H,W), 3x3 SAME zero-pad. Same edge-shfl mod.
__global__ void k_conv2(const float* __restrict__ f1, const float* __restrict__ w2,
                        const float* __restrict__ b2, float* __restrict__ f) {
    int b = blockIdx.x;
    int l = b & 7, y = b >> 3;
    int t = threadIdx.x;
    int lane = t & 63;
    int tc = t < 120 ? t : 119;
    int xi = tc * 4;
    float acc[2][4];
#pragma unroll
    for (int m = 0; m < 2; m++) {
        float bv = b2[m];
#pragma unroll
        for (int o = 0; o < 4; o++) acc[m][o] = bv;
    }
#pragma unroll 1
    for (int ic = 0; ic < MIDq; ic++) {
        const float* fin = f1 + (size_t)(l * MIDq + ic) * HWq;
        const float* wrow = w2 + ic * 9;
#pragma unroll
        for (int r = 0; r < 3; r++) {
            int yy = y + r - 1;
            if (yy < 0 || yy >= Hq) continue;
            const float* rp = fin + yy * Wq;
            float4 mid = *(const float4*)(rp + xi);
            float lft = __shfl_up(mid.w, 1, 64);
            if (lane == 0) lft = (xi == 0) ? 0.f : rp[xi - 1];
            float rgt = __shfl_down(mid.x, 1, 64);
            if (lane == 63) rgt = (xi + 4 < Wq) ? rp[xi + 4] : 0.f;
            if (xi + 4 >= Wq) rgt = 0.f;
            float in6[6] = {lft, mid.x, mid.y, mid.z, mid.w, rgt};
#pragma unroll
            for (int m = 0; m < 2; m++) {
                const float* wp = wrow + m * (MIDq * 9) + r * 3;
                float w0 = wp[0], w1v = wp[1], w2v = wp[2];
#pragma unroll
                for (int o = 0; o < 4; o++)
                    acc[m][o] = fmaf(w0, in6[o],
                                fmaf(w1v, in6[o + 1],
                                fmaf(w2v, in6[o + 2], acc[m][o])));
            }
        }
    }
    if (t < 120) {
        size_t rowoff = (size_t)y * Wq + xi;
#pragma unroll
        for (int m = 0; m < 2; m++) {
            float4 v = {acc[m][0], acc[m][1], acc[m][2], acc[m][3]};
            *(float4*)(f + (size_t)(l * 2 + m) * HWq + rowoff) = v;
        }
    }
}

// sobel (wrap-x, edge-y) + metric + tanh -> flow (L,2,H,W) (R5 exact)
__global__ void k_flow(const float* __restrict__ f, float* __restrict__ flow) {
    int idx = blockIdx.x * blockDim.x + threadIdx.x;
    if (idx >= Lq * HWq) return;
    int l = idx / HWq, rem = idx % HWq, y = rem / Wq, x = rem % Wq;
    const float* phi = f + (size_t)(l * 2 + 0) * HWq;
    const float* psi = f + (size_t)(l * 2 + 1) * HWq;
    float ph[3][3], ps[3][3];
#pragma unroll
    for (int i = 0; i < 3; i++) {
        int yy = y + i - 1;
        yy = yy < 0 ? 0 : (yy >= Hq ? Hq - 1 : yy);
#pragma unroll
        for (int j = 0; j < 3; j++) {
            int xx = x + j - 1;
            xx = (xx + Wq) % Wq;
            ph[i][j] = phi[yy * Wq + xx];
            ps[i][j] = psi[yy * Wq + xx];
        }
    }
    float gxp = (ph[0][2] - ph[0][0]) + 2.f * (ph[1][2] - ph[1][0]) + (ph[2][2] - ph[2][0]);
    float gyp = (ph[2][0] + 2.f * ph[2][1] + ph[2][2]) - (ph[0][0] + 2.f * ph[0][1] + ph[0][2]);
    float gxs = (ps[0][2] - ps[0][0]) + 2.f * (ps[1][2] - ps[1][0]) + (ps[2][2] - ps[2][0]);
    float gys = (ps[2][0] + 2.f * ps[2][1] + ps[2][2]) - (ps[0][0] + 2.f * ps[0][1] + ps[0][2]);
    float latf = (float)(-M_PI * 0.5 + (double)y * (M_PI / (double)(Hq - 1)));
    float metric = (float)(1.0 / (cos((double)latf) + 1e-6));
    float u = gxp * metric - gys;
    float v = gyp + gxs * metric;
    flow[(size_t)(l * 2 + 0) * HWq + rem] = tanhf(u);
    flow[(size_t)(l * 2 + 1) * HWq + rem] = tanhf(v);
}

// one-time: m0[px][c] = mean_r h0[c][px][r]   (h0: (C,H,W,R) fp32, R=8)
__global__ void k_m0(const float* __restrict__ h0, float* __restrict__ m0) {
    int px = blockIdx.x * 256 + threadIdx.x;
    const float4* h4 = (const float4*)h0;
    float4* mp = (float4*)(m0 + (size_t)px * Cq);
#pragma unroll
    for (int cq = 0; cq < 4; cq++) {
        float vals[4];
#pragma unroll
        for (int cc = 0; cc < 4; cc++) {
            int c = cq * 4 + cc;
            float4 a = h4[(size_t)(c * HWq + px) * 2];
            float4 b = h4[(size_t)(c * HWq + px) * 2 + 1];
            vals[cc] = (a.x + a.y + a.z + a.w + b.x + b.y + b.z + b.w) * 0.125f;
        }
        float4 o = {vals[0], vals[1], vals[2], vals[3]};
        mp[cq] = o;
    }
}

// Fused scan step (R10 exact: LDS transpose + per-wave rowsum + SE in LDS).
__global__ __launch_bounds__(1024) void k_step(const float* __restrict__ min_,
                       float* __restrict__ mout, const float* __restrict__ flow_l,
                       const float* __restrict__ xl, const float* __restrict__ listT,
                       int l,
                       const float* __restrict__ sw1, const float* __restrict__ sb1,
                       const float* __restrict__ sw2, const float* __restrict__ sb2,
                       float* __restrict__ out_l) {
    constexpr int STR = 17;                     // LDS row stride (coprime 32)
    __shared__ float sm[Wq * STR];
    __shared__ float csum[Cq];
    __shared__ float zl[SEM];
    __shared__ float gl[Cq];

    int y = blockIdx.x;
    int t = threadIdx.x;
    int wave = t >> 6, lane = t & 63;
    bool act = t < 2 * Wq;
    int px = act ? (t >> 1) : (Wq - 1);
    int half = t & 1;
    int c0 = half * 8;

    float dt = listT[l];
    float mn[8];
    {
        float u = flow_l[y * Wq + px];
        float v = flow_l[HWq + y * Wq + px];
        float gx = (px * (2.0f / (Wq - 1)) - 1.0f) - u * dt;
        float gy = (y * (2.0f / (Hq - 1)) - 1.0f) - v * dt;
        float xp = fminf(fmaxf((gx + 1.0f) * (Wq * 0.5f) - 0.5f, 0.0f), (float)(Wq - 1));
        float yp = fminf(fmaxf((gy + 1.0f) * (Hq * 0.5f) - 0.5f, 0.0f), (float)(Hq - 1));
        float x0f = floorf(xp), y0f = floorf(yp);
        float wx = xp - x0f, wy = yp - y0f;
        int x0 = (int)x0f, y0 = (int)y0f;
        int x1 = min(x0 + 1, Wq - 1), y1 = min(y0 + 1, Hq - 1);
        const float4* m4 = (const float4*)min_;
        size_t b00 = (size_t)(y0 * Wq + x0) * 4 + (half * 2);
        size_t b01 = (size_t)(y0 * Wq + x1) * 4 + (half * 2);
        size_t b10 = (size_t)(y1 * Wq + x0) * 4 + (half * 2);
        size_t b11 = (size_t)(y1 * Wq + x1) * 4 + (half * 2);
        float4 A0 = m4[b00], A1 = m4[b00 + 1];
        float4 B0 = m4[b01], B1 = m4[b01 + 1];
        float4 C0 = m4[b10], C1 = m4[b10 + 1];
        float4 D0 = m4[b11], D1 = m4[b11 + 1];
        float w00 = (1.f - wx) * (1.f - wy), w01 = wx * (1.f - wy);
        float w10 = (1.f - wx) * wy, w11 = wx * wy;
        const float* xb = xl + y * Wq + px;
        float xv[8];
#pragma unroll
        for (int j = 0; j < 8; j++) xv[j] = xb[(size_t)(c0 + j) * HWq];
        mn[0] = w00 * A0.x + w01 * B0.x + w10 * C0.x + w11 * D0.x + xv[0];
        mn[1] = w00 * A0.y + w01 * B0.y + w10 * C0.y + w11 * D0.y + xv[1];
        mn[2] = w00 * A0.z + w01 * B0.z + w10 * C0.z + w11 * D0.z + xv[2];
        mn[3] = w00 * A0.w + w01 * B0.w + w10 * C0.w + w11 * D0.w + xv[3];
        mn[4] = w00 * A1.x + w01 * B1.x + w10 * C1.x + w11 * D1.x + xv[4];
        mn[5] = w00 * A1.y + w01 * B1.y + w10 * C1.y + w11 * D1.y + xv[5];
        mn[6] = w00 * A1.z + w01 * B1.z + w10 * C1.z + w11 * D1.z + xv[6];
        mn[7] = w00 * A1.w + w01 * B1.w + w10 * C1.w + w11 * D1.w + xv[7];
    }
    if (act) {
        float4* mo = (float4*)(mout + (size_t)(y * Wq + px) * Cq + c0);
        float4 o0 = {mn[0], mn[1], mn[2], mn[3]};
        float4 o1 = {mn[4], mn[5], mn[6], mn[7]};
        mo[0] = o0;
        mo[1] = o1;
#pragma unroll
        for (int j = 0; j < 8; j++) sm[px * STR + c0 + j] = mn[j];
    }
    __syncthreads();
    {
        float s = 0.f;
#pragma unroll
        for (int k = 0; k < 8; k++) {
            int p = k * 64 + lane;
            if (p < Wq) s += sm[p * STR + wave];
        }
#pragma unroll
        for (int off = 32; off > 0; off >>= 1) s += __shfl_down(s, off, 64);
        if (lane == 0) csum[wave] = s;
    }
    __syncthreads();
    if (t < SEM) {
        float a = sb1[t];
#pragma unroll
        for (int i = 0; i < Cq; i++) a = fmaf(sw1[t * Cq + i], csum[i] * (1.0f / Wq), a);
        zl[t] = a * sigmoidf_(a);
    }
    __syncthreads();
    if (t < Cq) {
        float a = sb2[t];
#pragma unroll
        for (int m = 0; m < SEM; m++) a = fmaf(sw2[t * SEM + m], zl[m], a);
        gl[t] = sigmoidf_(a);
    }
    __syncthreads();
    if (act) {
        float* ob = out_l + y * Wq + px;
#pragma unroll
        for (int j = 0; j < 8; j++)
            ob[(size_t)(c0 + j) * HWq] = mn[j] * gl[c0 + j];
    }
}

extern "C" void kernel_launch(void* const* d_in, const int* in_sizes, int n_in,
                              void* d_out, int out_size, void* d_ws, size_t ws_size,
                              hipStream_t stream) {
    const float* x = (const float*)d_in[0];
    const float* h0 = (const float*)d_in[1];
    const float* listT = (const float*)d_in[2];
    const float* hw1 = (const float*)d_in[3];
    const float* hb1 = (const float*)d_in[4];
    const float* hw2 = (const float*)d_in[5];
    const float* hb2 = (const float*)d_in[6];
    const float* sw1 = (const float*)d_in[7];
    const float* sb1 = (const float*)d_in[8];
    const float* sw2 = (const float*)d_in[9];
    const float* sb2 = (const float*)d_in[10];
    float* out = (float*)d_out;
    char* ws = (char*)d_ws;

    size_t off = 0;
    float* flow = (float*)(ws + off); off += sizeof(float) * (size_t)Lq * 2 * HWq;
    float* f    = (float*)(ws + off); off += sizeof(float) * (size_t)Lq * 2 * HWq;
    float* f1   = (float*)(ws + off); off += sizeof(float) * (size_t)Lq * MIDq * HWq;
    float* mA   = (float*)(ws + off); off += sizeof(float) * (size_t)HWq * Cq;
    float* mB   = (float*)(ws + off); off += sizeof(float) * (size_t)HWq * Cq;

    k_conv1<<<Lq * Hq, 128, 0, stream>>>(x, hw1, hb1, f1);
    k_conv2<<<Lq * Hq, 128, 0, stream>>>(f1, hw2, hb2, f);
    k_flow<<<(Lq * HWq + 255) / 256, 256, 0, stream>>>(f, flow);
    k_m0<<<HWq / 256, 256, 0, stream>>>(h0, mA);

    float* bufs[2] = {mA, mB};
    for (int l = 0; l < Lq; l++) {
        float* min_ = bufs[l & 1];
        float* mout = bufs[(l + 1) & 1];
        k_step<<<Hq, 1024, 0, stream>>>(min_, mout, flow + (size_t)l * 2 * HWq,
                                        x + (size_t)l * Cq * HWq, listT, l,
                                        sw1, sb1, sw2, sb2,
                                        out + (size_t)l * Cq * HWq);
    }
}

// Round 18
// 163.902 us; speedup vs baseline: 1.3012x; 1.0404x over previous
//
#include <hip/hip_runtime.h>
#include <math.h>

constexpr int Lq = 8, Cq = 16, Hq = 240, Wq = 480, MIDq = 8, SEM = 4;
constexpr int HWq = Hq * Wq;

__device__ __forceinline__ float sigmoidf_(float v) { return 1.0f / (1.0f + expf(-v)); }

// conv1: x (L,16,H,W) -> silu -> f1 (L,8,H,W), 3x3 SAME zero-pad.
// R18: row-PAIR blocks, 256 thr (240 active, 2px x 2rows each). 4 input rows
// per 2 output rows = 1.5x fewer L1-missed lines than R5's 3, at the SAME
// 3840 total waves (R15's strip version cut lines but halved waves -> lost).
// Zero-pad via exact *0.0 scale; FMA chains per output unchanged.
__global__ __launch_bounds__(256, 2) void k_conv1(const float* __restrict__ x,
                        const float* __restrict__ w1,
                        const float* __restrict__ b1, float* __restrict__ f1) {
    int b = blockIdx.x;
    int l = b & 7, yp = b >> 3;        // yp 0..119
    int y0 = yp * 2;                   // output rows y0, y0+1
    int t = threadIdx.x;
    if (t >= 240) return;
    int xi = t * 2;
    bool lok = xi > 0, rok = xi + 2 < Wq;
    float acc[2][MIDq][2];
#pragma unroll
    for (int o = 0; o < 2; o++)
#pragma unroll
        for (int m = 0; m < MIDq; m++) {
            float bv = b1[m];
            acc[o][m][0] = bv;
            acc[o][m][1] = bv;
        }
    int ry[4]; float vs[4];
#pragma unroll
    for (int i = 0; i < 4; i++) {
        int r = y0 - 1 + i;
        vs[i] = (r >= 0 && r < Hq) ? 1.f : 0.f;
        ry[i] = r < 0 ? 0 : (r >= Hq - 1 ? Hq - 1 : r);
    }
    const float* xb = x + (size_t)l * Cq * HWq;
#pragma unroll 1
    for (int ic = 0; ic < Cq; ic++) {
        const float* cp = xb + (size_t)ic * HWq;
        float in4[4][4];               // 4 input rows x window {l, m0, m1, r}
#pragma unroll
        for (int i = 0; i < 4; i++) {
            const float* rp = cp + (size_t)ry[i] * Wq;
            float2 mid = *(const float2*)(rp + xi);
            float lf = lok ? rp[xi - 1] : 0.f;
            float rg = rok ? rp[xi + 2] : 0.f;
            float v = vs[i];
            in4[i][0] = lf * v;
            in4[i][1] = mid.x * v;
            in4[i][2] = mid.y * v;
            in4[i][3] = rg * v;
        }
        const float* wic = w1 + ic * 9;
#pragma unroll
        for (int o = 0; o < 2; o++) {
#pragma unroll
            for (int kr = 0; kr < 3; kr++) {
                const int i = o + kr;
#pragma unroll
                for (int m = 0; m < MIDq; m++) {
                    const float* wp = wic + (size_t)m * (Cq * 9) + kr * 3;
                    float w0 = wp[0], w1v = wp[1], w2v = wp[2];
                    acc[o][m][0] = fmaf(w0, in4[i][0],
                                   fmaf(w1v, in4[i][1],
                                   fmaf(w2v, in4[i][2], acc[o][m][0])));
                    acc[o][m][1] = fmaf(w0, in4[i][1],
                                   fmaf(w1v, in4[i][2],
                                   fmaf(w2v, in4[i][3], acc[o][m][1])));
                }
            }
        }
    }
#pragma unroll
    for (int o = 0; o < 2; o++) {
        size_t rowoff = (size_t)(y0 + o) * Wq + xi;
#pragma unroll
        for (int m = 0; m < MIDq; m++) {
            float a0 = acc[o][m][0], a1 = acc[o][m][1];
            float2 v = {a0 * sigmoidf_(a0), a1 * sigmoidf_(a1)};
            *(float2*)(f1 + (size_t)(l * MIDq + m) * HWq + rowoff) = v;
        }
    }
}

// conv2: f1 (L,8,H,W) -> f (L,2,H,W), 3x3 SAME zero-pad. (R5/R10 exact)
__global__ void k_conv2(const float* __restrict__ f1, const float* __restrict__ w2,
                        const float* __restrict__ b2, float* __restrict__ f) {
    int b = blockIdx.x;
    int l = b & 7, y = b >> 3;
    int t = threadIdx.x;
    if (t >= Wq / 4) return;
    int xi = t * 4;
    float acc[2][4];
#pragma unroll
    for (int m = 0; m < 2; m++) {
        float bv = b2[m];
#pragma unroll
        for (int o = 0; o < 4; o++) acc[m][o] = bv;
    }
#pragma unroll 1
    for (int ic = 0; ic < MIDq; ic++) {
        const float* fin = f1 + (size_t)(l * MIDq + ic) * HWq;
        const float* wrow = w2 + ic * 9;
#pragma unroll
        for (int r = 0; r < 3; r++) {
            int yy = y + r - 1;
            if (yy < 0 || yy >= Hq) continue;
            const float* rp = fin + yy * Wq;
            float4 mid = *(const float4*)(rp + xi);
            float lft = (xi > 0) ? rp[xi - 1] : 0.f;
            float rgt = (xi + 4 < Wq) ? rp[xi + 4] : 0.f;
            float in6[6] = {lft, mid.x, mid.y, mid.z, mid.w, rgt};
#pragma unroll
            for (int m = 0; m < 2; m++) {
                const float* wp = wrow + m * (MIDq * 9) + r * 3;
                float w0 = wp[0], w1v = wp[1], w2v = wp[2];
#pragma unroll
                for (int o = 0; o < 4; o++)
                    acc[m][o] = fmaf(w0, in6[o],
                                fmaf(w1v, in6[o + 1],
                                fmaf(w2v, in6[o + 2], acc[m][o])));
            }
        }
    }
    size_t rowoff = (size_t)y * Wq + xi;
#pragma unroll
    for (int m = 0; m < 2; m++) {
        float4 v = {acc[m][0], acc[m][1], acc[m][2], acc[m][3]};
        *(float4*)(f + (size_t)(l * 2 + m) * HWq + rowoff) = v;
    }
}

// sobel (wrap-x, edge-y) + metric + tanh -> flow (L,2,H,W) (R5 exact)
__global__ void k_flow(const float* __restrict__ f, float* __restrict__ flow) {
    int idx = blockIdx.x * blockDim.x + threadIdx.x;
    if (idx >= Lq * HWq) return;
    int l = idx / HWq, rem = idx % HWq, y = rem / Wq, x = rem % Wq;
    const float* phi = f + (size_t)(l * 2 + 0) * HWq;
    const float* psi = f + (size_t)(l * 2 + 1) * HWq;
    float ph[3][3], ps[3][3];
#pragma unroll
    for (int i = 0; i < 3; i++) {
        int yy = y + i - 1;
        yy = yy < 0 ? 0 : (yy >= Hq ? Hq - 1 : yy);
#pragma unroll
        for (int j = 0; j < 3; j++) {
            int xx = x + j - 1;
            xx = (xx + Wq) % Wq;
            ph[i][j] = phi[yy * Wq + xx];
            ps[i][j] = psi[yy * Wq + xx];
        }
    }
    float gxp = (ph[0][2] - ph[0][0]) + 2.f * (ph[1][2] - ph[1][0]) + (ph[2][2] - ph[2][0]);
    float gyp = (ph[2][0] + 2.f * ph[2][1] + ph[2][2]) - (ph[0][0] + 2.f * ph[0][1] + ph[0][2]);
    float gxs = (ps[0][2] - ps[0][0]) + 2.f * (ps[1][2] - ps[1][0]) + (ps[2][2] - ps[2][0]);
    float gys = (ps[2][0] + 2.f * ps[2][1] + ps[2][2]) - (ps[0][0] + 2.f * ps[0][1] + ps[0][2]);
    float latf = (float)(-M_PI * 0.5 + (double)y * (M_PI / (double)(Hq - 1)));
    float metric = (float)(1.0 / (cos((double)latf) + 1e-6));
    float u = gxp * metric - gys;
    float v = gyp + gxs * metric;
    flow[(size_t)(l * 2 + 0) * HWq + rem] = tanhf(u);
    flow[(size_t)(l * 2 + 1) * HWq + rem] = tanhf(v);
}

// one-time: m0[px][c] = mean_r h0[c][px][r]   (h0: (C,H,W,R) fp32, R=8)
__global__ void k_m0(const float* __restrict__ h0, float* __restrict__ m0) {
    int px = blockIdx.x * 256 + threadIdx.x;
    const float4* h4 = (const float4*)h0;
    float4* mp = (float4*)(m0 + (size_t)px * Cq);
#pragma unroll
    for (int cq = 0; cq < 4; cq++) {
        float vals[4];
#pragma unroll
        for (int cc = 0; cc < 4; cc++) {
            int c = cq * 4 + cc;
            float4 a = h4[(size_t)(c * HWq + px) * 2];
            float4 b = h4[(size_t)(c * HWq + px) * 2 + 1];
            vals[cc] = (a.x + a.y + a.z + a.w + b.x + b.y + b.z + b.w) * 0.125f;
        }
        float4 o = {vals[0], vals[1], vals[2], vals[3]};
        mp[cq] = o;
    }
}

// Fused scan step (R10 exact: LDS transpose + per-wave rowsum + SE in LDS).
__global__ __launch_bounds__(1024) void k_step(const float* __restrict__ min_,
                       float* __restrict__ mout, const float* __restrict__ flow_l,
                       const float* __restrict__ xl, const float* __restrict__ listT,
                       int l,
                       const float* __restrict__ sw1, const float* __restrict__ sb1,
                       const float* __restrict__ sw2, const float* __restrict__ sb2,
                       float* __restrict__ out_l) {
    constexpr int STR = 17;                     // LDS row stride (coprime 32)
    __shared__ float sm[Wq * STR];
    __shared__ float csum[Cq];
    __shared__ float zl[SEM];
    __shared__ float gl[Cq];

    int y = blockIdx.x;
    int t = threadIdx.x;
    int wave = t >> 6, lane = t & 63;
    bool act = t < 2 * Wq;
    int px = act ? (t >> 1) : (Wq - 1);
    int half = t & 1;
    int c0 = half * 8;

    float dt = listT[l];
    float mn[8];
    {
        float u = flow_l[y * Wq + px];
        float v = flow_l[HWq + y * Wq + px];
        float gx = (px * (2.0f / (Wq - 1)) - 1.0f) - u * dt;
        float gy = (y * (2.0f / (Hq - 1)) - 1.0f) - v * dt;
        float xp = fminf(fmaxf((gx + 1.0f) * (Wq * 0.5f) - 0.5f, 0.0f), (float)(Wq - 1));
        float yp = fminf(fmaxf((gy + 1.0f) * (Hq * 0.5f) - 0.5f, 0.0f), (float)(Hq - 1));
        float x0f = floorf(xp), y0f = floorf(yp);
        float wx = xp - x0f, wy = yp - y0f;
        int x0 = (int)x0f, y0 = (int)y0f;
        int x1 = min(x0 + 1, Wq - 1), y1 = min(y0 + 1, Hq - 1);
        const float4* m4 = (const float4*)min_;
        size_t b00 = (size_t)(y0 * Wq + x0) * 4 + (half * 2);
        size_t b01 = (size_t)(y0 * Wq + x1) * 4 + (half * 2);
        size_t b10 = (size_t)(y1 * Wq + x0) * 4 + (half * 2);
        size_t b11 = (size_t)(y1 * Wq + x1) * 4 + (half * 2);
        float4 A0 = m4[b00], A1 = m4[b00 + 1];
        float4 B0 = m4[b01], B1 = m4[b01 + 1];
        float4 C0 = m4[b10], C1 = m4[b10 + 1];
        float4 D0 = m4[b11], D1 = m4[b11 + 1];
        float w00 = (1.f - wx) * (1.f - wy), w01 = wx * (1.f - wy);
        float w10 = (1.f - wx) * wy, w11 = wx * wy;
        const float* xb = xl + y * Wq + px;
        float xv[8];
#pragma unroll
        for (int j = 0; j < 8; j++) xv[j] = xb[(size_t)(c0 + j) * HWq];
        mn[0] = w00 * A0.x + w01 * B0.x + w10 * C0.x + w11 * D0.x + xv[0];
        mn[1] = w00 * A0.y + w01 * B0.y + w10 * C0.y + w11 * D0.y + xv[1];
        mn[2] = w00 * A0.z + w01 * B0.z + w10 * C0.z + w11 * D0.z + xv[2];
        mn[3] = w00 * A0.w + w01 * B0.w + w10 * C0.w + w11 * D0.w + xv[3];
        mn[4] = w00 * A1.x + w01 * B1.x + w10 * C1.x + w11 * D1.x + xv[4];
        mn[5] = w00 * A1.y + w01 * B1.y + w10 * C1.y + w11 * D1.y + xv[5];
        mn[6] = w00 * A1.z + w01 * B1.z + w10 * C1.z + w11 * D1.z + xv[6];
        mn[7] = w00 * A1.w + w01 * B1.w + w10 * C1.w + w11 * D1.w + xv[7];
    }
    if (act) {
        float4* mo = (float4*)(mout + (size_t)(y * Wq + px) * Cq + c0);
        float4 o0 = {mn[0], mn[1], mn[2], mn[3]};
        float4 o1 = {mn[4], mn[5], mn[6], mn[7]};
        mo[0] = o0;
        mo[1] = o1;
#pragma unroll
        for (int j = 0; j < 8; j++) sm[px * STR + c0 + j] = mn[j];
    }
    __syncthreads();
    {
        float s = 0.f;
#pragma unroll
        for (int k = 0; k < 8; k++) {
            int p = k * 64 + lane;
            if (p < Wq) s += sm[p * STR + wave];
        }
#pragma unroll
        for (int off = 32; off > 0; off >>= 1) s += __shfl_down(s, off, 64);
        if (lane == 0) csum[wave] = s;
    }
    __syncthreads();
    if (t < SEM) {
        float a = sb1[t];
#pragma unroll
        for (int i = 0; i < Cq; i++) a = fmaf(sw1[t * Cq + i], csum[i] * (1.0f / Wq), a);
        zl[t] = a * sigmoidf_(a);
    }
    __syncthreads();
    if (t < Cq) {
        float a = sb2[t];
#pragma unroll
        for (int m = 0; m < SEM; m++) a = fmaf(sw2[t * SEM + m], zl[m], a);
        gl[t] = sigmoidf_(a);
    }
    __syncthreads();
    if (act) {
        float* ob = out_l + y * Wq + px;
#pragma unroll
        for (int j = 0; j < 8; j++)
            ob[(size_t)(c0 + j) * HWq] = mn[j] * gl[c0 + j];
    }
}

extern "C" void kernel_launch(void* const* d_in, const int* in_sizes, int n_in,
                              void* d_out, int out_size, void* d_ws, size_t ws_size,
                              hipStream_t stream) {
    const float* x = (const float*)d_in[0];
    const float* h0 = (const float*)d_in[1];
    const float* listT = (const float*)d_in[2];
    const float* hw1 = (const float*)d_in[3];
    const float* hb1 = (const float*)d_in[4];
    const float* hw2 = (const float*)d_in[5];
    const float* hb2 = (const float*)d_in[6];
    const float* sw1 = (const float*)d_in[7];
    const float* sb1 = (const float*)d_in[8];
    const float* sw2 = (const float*)d_in[9];
    const float* sb2 = (const float*)d_in[10];
    float* out = (float*)d_out;
    char* ws = (char*)d_ws;

    size_t off = 0;
    float* flow = (float*)(ws + off); off += sizeof(float) * (size_t)Lq * 2 * HWq;
    float* f    = (float*)(ws + off); off += sizeof(float) * (size_t)Lq * 2 * HWq;
    float* f1   = (float*)(ws + off); off += sizeof(float) * (size_t)Lq * MIDq * HWq;
    float* mA   = (float*)(ws + off); off += sizeof(float) * (size_t)HWq * Cq;
    float* mB   = (float*)(ws + off); off += sizeof(float) * (size_t)HWq * Cq;

    k_conv1<<<Lq * (Hq / 2), 256, 0, stream>>>(x, hw1, hb1, f1);
    k_conv2<<<Lq * Hq, 128, 0, stream>>>(f1, hw2, hb2, f);
    k_flow<<<(Lq * HWq + 255) / 256, 256, 0, stream>>>(f, flow);
    k_m0<<<HWq / 256, 256, 0, stream>>>(h0, mA);

    float* bufs[2] = {mA, mB};
    for (int l = 0; l < Lq; l++) {
        float* min_ = bufs[l & 1];
        float* mout = bufs[(l + 1) & 1];
        k_step<<<Hq, 1024, 0, stream>>>(min_, mout, flow + (size_t)l * 2 * HWq,
                                        x + (size_t)l * Cq * HWq, listT, l,
                                        sw1, sb1, sw2, sb2,
                                        out + (size_t)l * Cq * HWq);
    }
}

// Round 19
// 153.887 us; speedup vs baseline: 1.3859x; 1.0651x over previous
//
#include <hip/hip_runtime.h>
#include <hip/hip_fp16.h>
#include <math.h>

constexpr int Lq = 8, Cq = 16, Hq = 240, Wq = 480, MIDq = 8, SEM = 4;
constexpr int HWq = Hq * Wq;

__device__ __forceinline__ float sigmoidf_(float v) { return 1.0f / (1.0f + expf(-v)); }

struct alignas(16) h8 { __half v[8]; };

// conv1: x (L,16,H,W) -> silu -> f1 (L,8,H,W), 3x3 SAME zero-pad.
// R19: R13-exact (best measured conv1: 57.6us). 10 restructures (occupancy,
// ILP, LDS, strips, shfl, row-pairs) all landed 57-113us -> this latency-bound
// equilibrium is conv1's floor; keeping the best form.
__global__ __launch_bounds__(128, 4) void k_conv1(const float* __restrict__ x,
                        const float* __restrict__ w1,
                        const float* __restrict__ b1, float* __restrict__ f1) {
    int b = blockIdx.x;
    int l = b & 7, y = b >> 3;
    int t = threadIdx.x;
    if (t >= 120) return;
    int xi = t * 4;
    float acc[MIDq][4];
#pragma unroll
    for (int m = 0; m < MIDq; m++) {
        float bv = b1[m];
#pragma unroll
        for (int o = 0; o < 4; o++) acc[m][o] = bv;
    }
    int yy0 = y > 0 ? y - 1 : 0;
    int yy2 = y < Hq - 1 ? y + 1 : Hq - 1;
    float v0 = y > 0 ? 1.f : 0.f;
    float v2 = y < Hq - 1 ? 1.f : 0.f;
    bool lok = xi > 0, rok = xi + 4 < Wq;
    const float* xb = x + (size_t)l * Cq * HWq;
#pragma unroll 1
    for (int ic = 0; ic < Cq; ic++) {
        const float* p0 = xb + (size_t)ic * HWq + yy0 * Wq;
        const float* p1 = xb + (size_t)ic * HWq + y * Wq;
        const float* p2 = xb + (size_t)ic * HWq + yy2 * Wq;
        float4 m0 = *(const float4*)(p0 + xi);
        float4 m1 = *(const float4*)(p1 + xi);
        float4 m2 = *(const float4*)(p2 + xi);
        float l0 = lok ? p0[xi - 1] : 0.f;
        float l1 = lok ? p1[xi - 1] : 0.f;
        float l2 = lok ? p2[xi - 1] : 0.f;
        float r0 = rok ? p0[xi + 4] : 0.f;
        float r1 = rok ? p1[xi + 4] : 0.f;
        float r2 = rok ? p2[xi + 4] : 0.f;
        float in0[6] = {l0 * v0, m0.x * v0, m0.y * v0, m0.z * v0, m0.w * v0, r0 * v0};
        float in1[6] = {l1, m1.x, m1.y, m1.z, m1.w, r1};
        float in2[6] = {l2 * v2, m2.x * v2, m2.y * v2, m2.z * v2, m2.w * v2, r2 * v2};
        const float* wic = w1 + ic * 9;
#pragma unroll
        for (int m = 0; m < MIDq; m++) {
            const float* wp = wic + (size_t)m * (Cq * 9);
            float w00 = wp[0], w01 = wp[1], w02 = wp[2];
            float w10 = wp[3], w11 = wp[4], w12 = wp[5];
            float w20 = wp[6], w21 = wp[7], w22 = wp[8];
#pragma unroll
            for (int o = 0; o < 4; o++) {
                float a = acc[m][o];
                a = fmaf(w00, in0[o], fmaf(w01, in0[o + 1], fmaf(w02, in0[o + 2], a)));
                a = fmaf(w10, in1[o], fmaf(w11, in1[o + 1], fmaf(w12, in1[o + 2], a)));
                a = fmaf(w20, in2[o], fmaf(w21, in2[o + 1], fmaf(w22, in2[o + 2], a)));
                acc[m][o] = a;
            }
        }
    }
    size_t rowoff = (size_t)y * Wq + xi;
#pragma unroll
    for (int m = 0; m < MIDq; m++) {
        float4 v;
        float a0 = acc[m][0], a1 = acc[m][1], a2 = acc[m][2], a3 = acc[m][3];
        v.x = a0 * sigmoidf_(a0);
        v.y = a1 * sigmoidf_(a1);
        v.z = a2 * sigmoidf_(a2);
        v.w = a3 * sigmoidf_(a3);
        *(float4*)(f1 + (size_t)(l * MIDq + m) * HWq + rowoff) = v;
    }
}

// conv2: f1 (L,8,H,W) -> f (L,2,H,W), 3x3 SAME zero-pad. (R13-exact)
__global__ __launch_bounds__(128, 4) void k_conv2(const float* __restrict__ f1,
                        const float* __restrict__ w2,
                        const float* __restrict__ b2, float* __restrict__ f) {
    int b = blockIdx.x;
    int l = b & 7, y = b >> 3;
    int t = threadIdx.x;
    if (t >= 120) return;
    int xi = t * 4;
    float acc[2][4];
#pragma unroll
    for (int m = 0; m < 2; m++) {
        float bv = b2[m];
#pragma unroll
        for (int o = 0; o < 4; o++) acc[m][o] = bv;
    }
    int yy0 = y > 0 ? y - 1 : 0;
    int yy2 = y < Hq - 1 ? y + 1 : Hq - 1;
    float v0 = y > 0 ? 1.f : 0.f;
    float v2 = y < Hq - 1 ? 1.f : 0.f;
    bool lok = xi > 0, rok = xi + 4 < Wq;
    const float* fb = f1 + (size_t)l * MIDq * HWq;
#pragma unroll 1
    for (int ic = 0; ic < MIDq; ic++) {
        const float* p0 = fb + (size_t)ic * HWq + yy0 * Wq;
        const float* p1 = fb + (size_t)ic * HWq + y * Wq;
        const float* p2 = fb + (size_t)ic * HWq + yy2 * Wq;
        float4 m0 = *(const float4*)(p0 + xi);
        float4 m1 = *(const float4*)(p1 + xi);
        float4 m2 = *(const float4*)(p2 + xi);
        float l0 = lok ? p0[xi - 1] : 0.f;
        float l1 = lok ? p1[xi - 1] : 0.f;
        float l2 = lok ? p2[xi - 1] : 0.f;
        float r0 = rok ? p0[xi + 4] : 0.f;
        float r1 = rok ? p1[xi + 4] : 0.f;
        float r2 = rok ? p2[xi + 4] : 0.f;
        float in0[6] = {l0 * v0, m0.x * v0, m0.y * v0, m0.z * v0, m0.w * v0, r0 * v0};
        float in1[6] = {l1, m1.x, m1.y, m1.z, m1.w, r1};
        float in2[6] = {l2 * v2, m2.x * v2, m2.y * v2, m2.z * v2, m2.w * v2, r2 * v2};
        const float* wic = w2 + ic * 9;
#pragma unroll
        for (int m = 0; m < 2; m++) {
            const float* wp = wic + (size_t)m * (MIDq * 9);
            float w00 = wp[0], w01 = wp[1], w02 = wp[2];
            float w10 = wp[3], w11 = wp[4], w12 = wp[5];
            float w20 = wp[6], w21 = wp[7], w22 = wp[8];
#pragma unroll
            for (int o = 0; o < 4; o++) {
                float a = acc[m][o];
                a = fmaf(w00, in0[o], fmaf(w01, in0[o + 1], fmaf(w02, in0[o + 2], a)));
                a = fmaf(w10, in1[o], fmaf(w11, in1[o + 1], fmaf(w12, in1[o + 2], a)));
                a = fmaf(w20, in2[o], fmaf(w21, in2[o + 1], fmaf(w22, in2[o + 2], a)));
                acc[m][o] = a;
            }
        }
    }
    size_t rowoff = (size_t)y * Wq + xi;
#pragma unroll
    for (int m = 0; m < 2; m++) {
        float4 v = {acc[m][0], acc[m][1], acc[m][2], acc[m][3]};
        *(float4*)(f + (size_t)(l * 2 + m) * HWq + rowoff) = v;
    }
}

// sobel (wrap-x, edge-y) + metric + tanh -> flow (L,2,H,W) (R5 exact)
__global__ void k_flow(const float* __restrict__ f, float* __restrict__ flow) {
    int idx = blockIdx.x * blockDim.x + threadIdx.x;
    if (idx >= Lq * HWq) return;
    int l = idx / HWq, rem = idx % HWq, y = rem / Wq, x = rem % Wq;
    const float* phi = f + (size_t)(l * 2 + 0) * HWq;
    const float* psi = f + (size_t)(l * 2 + 1) * HWq;
    float ph[3][3], ps[3][3];
#pragma unroll
    for (int i = 0; i < 3; i++) {
        int yy = y + i - 1;
        yy = yy < 0 ? 0 : (yy >= Hq ? Hq - 1 : yy);
#pragma unroll
        for (int j = 0; j < 3; j++) {
            int xx = x + j - 1;
            xx = (xx + Wq) % Wq;
            ph[i][j] = phi[yy * Wq + xx];
            ps[i][j] = psi[yy * Wq + xx];
        }
    }
    float gxp = (ph[0][2] - ph[0][0]) + 2.f * (ph[1][2] - ph[1][0]) + (ph[2][2] - ph[2][0]);
    float gyp = (ph[2][0] + 2.f * ph[2][1] + ph[2][2]) - (ph[0][0] + 2.f * ph[0][1] + ph[0][2]);
    float gxs = (ps[0][2] - ps[0][0]) + 2.f * (ps[1][2] - ps[1][0]) + (ps[2][2] - ps[2][0]);
    float gys = (ps[2][0] + 2.f * ps[2][1] + ps[2][2]) - (ps[0][0] + 2.f * ps[0][1] + ps[0][2]);
    float latf = (float)(-M_PI * 0.5 + (double)y * (M_PI / (double)(Hq - 1)));
    float metric = (float)(1.0 / (cos((double)latf) + 1e-6));
    float u = gxp * metric - gys;
    float v = gyp + gxs * metric;
    flow[(size_t)(l * 2 + 0) * HWq + rem] = tanhf(u);
    flow[(size_t)(l * 2 + 1) * HWq + rem] = tanhf(v);
}

// one-time: m0[px][c] = mean_r h0[c][px][r] -> fp16 (h0: (C,H,W,R) fp32)
__global__ void k_m0(const float* __restrict__ h0, h8* __restrict__ m0) {
    int px = blockIdx.x * 256 + threadIdx.x;
    const float4* h4 = (const float4*)h0;
#pragma unroll
    for (int half = 0; half < 2; half++) {
        h8 o;
#pragma unroll
        for (int cc = 0; cc < 8; cc++) {
            int c = half * 8 + cc;
            float4 a = h4[(size_t)(c * HWq + px) * 2];
            float4 b = h4[(size_t)(c * HWq + px) * 2 + 1];
            o.v[cc] = __float2half((a.x + a.y + a.z + a.w + b.x + b.y + b.z + b.w) * 0.125f);
        }
        m0[(size_t)px * 2 + half] = o;
    }
}

// Fused scan step. R19: m state fp16 -> ONE 16B gather load per corner per
// lane (was 2 float4), m traffic halved. Output uses pre-rounding fp32 mn
// (same recipe as R5-R8 fp16-h, where absmax stayed exactly 0.03125).
__global__ __launch_bounds__(1024) void k_step(const h8* __restrict__ min_,
                       h8* __restrict__ mout, const float* __restrict__ flow_l,
                       const float* __restrict__ xl, const float* __restrict__ listT,
                       int l,
                       const float* __restrict__ sw1, const float* __restrict__ sb1,
                       const float* __restrict__ sw2, const float* __restrict__ sb2,
                       float* __restrict__ out_l) {
    constexpr int STR = 17;
    __shared__ float sm[Wq * STR];
    __shared__ float csum[Cq];
    __shared__ float zl[SEM];
    __shared__ float gl[Cq];

    int y = blockIdx.x;
    int t = threadIdx.x;
    int wave = t >> 6, lane = t & 63;
    bool act = t < 2 * Wq;
    int px = act ? (t >> 1) : (Wq - 1);
    int half = t & 1;
    int c0 = half * 8;

    float dt = listT[l];
    float mn[8];
    {
        float u = flow_l[y * Wq + px];
        float v = flow_l[HWq + y * Wq + px];
        float gx = (px * (2.0f / (Wq - 1)) - 1.0f) - u * dt;
        float gy = (y * (2.0f / (Hq - 1)) - 1.0f) - v * dt;
        float xp = fminf(fmaxf((gx + 1.0f) * (Wq * 0.5f) - 0.5f, 0.0f), (float)(Wq - 1));
        float yp = fminf(fmaxf((gy + 1.0f) * (Hq * 0.5f) - 0.5f, 0.0f), (float)(Hq - 1));
        float x0f = floorf(xp), y0f = floorf(yp);
        float wx = xp - x0f, wy = yp - y0f;
        int x0 = (int)x0f, y0 = (int)y0f;
        int x1 = min(x0 + 1, Wq - 1), y1 = min(y0 + 1, Hq - 1);
        // one h8 (16B) per corner per lane
        h8 A = min_[(size_t)(y0 * Wq + x0) * 2 + half];
        h8 B = min_[(size_t)(y0 * Wq + x1) * 2 + half];
        h8 C = min_[(size_t)(y1 * Wq + x0) * 2 + half];
        h8 D = min_[(size_t)(y1 * Wq + x1) * 2 + half];
        float w00 = (1.f - wx) * (1.f - wy), w01 = wx * (1.f - wy);
        float w10 = (1.f - wx) * wy, w11 = wx * wy;
        const float* xb = xl + y * Wq + px;
#pragma unroll
        for (int j = 0; j < 8; j++) {
            float xv = xb[(size_t)(c0 + j) * HWq];
            mn[j] = w00 * __half2float(A.v[j]) + w01 * __half2float(B.v[j]) +
                    w10 * __half2float(C.v[j]) + w11 * __half2float(D.v[j]) + xv;
        }
    }
    if (act) {
        h8 o;
#pragma unroll
        for (int j = 0; j < 8; j++) o.v[j] = __float2half(mn[j]);
        mout[(size_t)(y * Wq + px) * 2 + half] = o;
#pragma unroll
        for (int j = 0; j < 8; j++) sm[px * STR + c0 + j] = mn[j];
    }
    __syncthreads();
    {
        float s = 0.f;
#pragma unroll
        for (int k = 0; k < 8; k++) {
            int p = k * 64 + lane;
            if (p < Wq) s += sm[p * STR + wave];
        }
#pragma unroll
        for (int off = 32; off > 0; off >>= 1) s += __shfl_down(s, off, 64);
        if (lane == 0) csum[wave] = s;
    }
    __syncthreads();
    if (t < SEM) {
        float a = sb1[t];
#pragma unroll
        for (int i = 0; i < Cq; i++) a = fmaf(sw1[t * Cq + i], csum[i] * (1.0f / Wq), a);
        zl[t] = a * sigmoidf_(a);
    }
    __syncthreads();
    if (t < Cq) {
        float a = sb2[t];
#pragma unroll
        for (int m = 0; m < SEM; m++) a = fmaf(sw2[t * SEM + m], zl[m], a);
        gl[t] = sigmoidf_(a);
    }
    __syncthreads();
    if (act) {
        float* ob = out_l + y * Wq + px;
#pragma unroll
        for (int j = 0; j < 8; j++)
            ob[(size_t)(c0 + j) * HWq] = mn[j] * gl[c0 + j];
    }
}

extern "C" void kernel_launch(void* const* d_in, const int* in_sizes, int n_in,
                              void* d_out, int out_size, void* d_ws, size_t ws_size,
                              hipStream_t stream) {
    const float* x = (const float*)d_in[0];
    const float* h0 = (const float*)d_in[1];
    const float* listT = (const float*)d_in[2];
    const float* hw1 = (const float*)d_in[3];
    const float* hb1 = (const float*)d_in[4];
    const float* hw2 = (const float*)d_in[5];
    const float* hb2 = (const float*)d_in[6];
    const float* sw1 = (const float*)d_in[7];
    const float* sb1 = (const float*)d_in[8];
    const float* sw2 = (const float*)d_in[9];
    const float* sb2 = (const float*)d_in[10];
    float* out = (float*)d_out;
    char* ws = (char*)d_ws;

    size_t off = 0;
    float* flow = (float*)(ws + off); off += sizeof(float) * (size_t)Lq * 2 * HWq;
    float* f    = (float*)(ws + off); off += sizeof(float) * (size_t)Lq * 2 * HWq;
    float* f1   = (float*)(ws + off); off += sizeof(float) * (size_t)Lq * MIDq * HWq;
    h8* mA      = (h8*)(ws + off);    off += sizeof(h8) * (size_t)HWq * 2;
    h8* mB      = (h8*)(ws + off);    off += sizeof(h8) * (size_t)HWq * 2;

    k_conv1<<<Lq * Hq, 128, 0, stream>>>(x, hw1, hb1, f1);
    k_conv2<<<Lq * Hq, 128, 0, stream>>>(f1, hw2, hb2, f);
    k_flow<<<(Lq * HWq + 255) / 256, 256, 0, stream>>>(f, flow);
    k_m0<<<HWq / 256, 256, 0, stream>>>(h0, mA);

    h8* bufs[2] = {mA, mB};
    for (int l = 0; l < Lq; l++) {
        h8* min_ = bufs[l & 1];
        h8* mout = bufs[(l + 1) & 1];
        k_step<<<Hq, 1024, 0, stream>>>(min_, mout, flow + (size_t)l * 2 * HWq,
                                        x + (size_t)l * Cq * HWq, listT, l,
                                        sw1, sb1, sw2, sb2,
                                        out + (size_t)l * Cq * HWq);
    }
}